// Round 3
// baseline (955.211 us; speedup 1.0000x reference)
//
#include <hip/hip_runtime.h>

#define NN 100000
#define NE 3200000
#define NB 1563        // ceil(NN/64), 64-node buckets
#define BCAP 2560      // bucket capacity: mean 2048, +11 sigma

__device__ __forceinline__ float lanebc(float v, int l) {
  return __int_as_float(__builtin_amdgcn_readlane(__float_as_int(v), l));
}

// ---------------- h0 = concat(node_type, LN(onehot@We+be), other) ----------------
__global__ __launch_bounds__(256) void k_h0(const float* __restrict__ x,
    const float* __restrict__ We, const float* __restrict__ be,
    const float* __restrict__ lg, const float* __restrict__ lb,
    float* __restrict__ h0)
{
  __shared__ float xs[256 * 35];
  int tid = threadIdx.x;
  int base_node = blockIdx.x * 256;
  int nvalid = NN - base_node; if (nvalid > 256) nvalid = 256;
  int total = nvalid * 35;
  const float* srcp = x + (size_t)base_node * 35;
  for (int j = tid; j < total; j += 256) xs[j] = srcp[j];
  __syncthreads();
  int i = base_node + tid;
  if (i >= NN) return;
  const float* xr = xs + tid * 35;
  float e[8];
  #pragma unroll
  for (int j = 0; j < 8; ++j) e[j] = be[j];
  #pragma unroll
  for (int k = 0; k < 26; ++k) {
    float o = xr[6 + k];
    #pragma unroll
    for (int j = 0; j < 8; ++j) e[j] = fmaf(o, We[k * 8 + j], e[j]);
  }
  float mu = 0.f;
  #pragma unroll
  for (int j = 0; j < 8; ++j) mu += e[j];
  mu *= 0.125f;
  float var = 0.f;
  #pragma unroll
  for (int j = 0; j < 8; ++j) { float d = e[j] - mu; var = fmaf(d, d, var); }
  var *= 0.125f;
  float rs = rsqrtf(var + 1e-5f);
  float* hr = h0 + (size_t)i * 17;
  #pragma unroll
  for (int j = 0; j < 6; ++j) hr[j] = xr[j];
  #pragma unroll
  for (int j = 0; j < 8; ++j) hr[6 + j] = (e[j] - mu) * rs * lg[j] + lb[j];
  #pragma unroll
  for (int j = 0; j < 3; ++j) hr[14 + j] = xr[32 + j];
}

// ---------------- pass 1: bin edges into 64-node buckets (dense write frontier) ----------------
__global__ __launch_bounds__(256) void k_bin(const int* __restrict__ ei,
    int* __restrict__ bcur, int* __restrict__ ebuf)
{
  int t = blockIdx.x * 256 + threadIdx.x;
  int base = t * 4;
  if (base >= NE) return;
  int4 s4 = *(const int4*)(ei + base);
  int4 d4 = *(const int4*)(ei + NE + base);
  int b0 = d4.x >> 6, b1 = d4.y >> 6, b2 = d4.z >> 6, b3 = d4.w >> 6;
  int p0 = atomicAdd(&bcur[b0], 1);
  int p1 = atomicAdd(&bcur[b1], 1);
  int p2 = atomicAdd(&bcur[b2], 1);
  int p3 = atomicAdd(&bcur[b3], 1);
  if (p0 < BCAP) ebuf[b0 * BCAP + p0] = (s4.x << 6) | (d4.x & 63);
  if (p1 < BCAP) ebuf[b1 * BCAP + p1] = (s4.y << 6) | (d4.y & 63);
  if (p2 < BCAP) ebuf[b2 * BCAP + p2] = (s4.z << 6) | (d4.z & 63);
  if (p3 < BCAP) ebuf[b3 * BCAP + p3] = (s4.w << 6) | (d4.w & 63);
}

// ---------------- pass 2: scan bucket counts -> bucket bases ----------------
__global__ __launch_bounds__(256) void k_bscan(const int* __restrict__ bcur,
    int* __restrict__ bbase, int* __restrict__ row_start)
{
  __shared__ int sd[256];
  int t = threadIdx.x;
  int c[7]; int s = 0;
  #pragma unroll
  for (int j = 0; j < 7; ++j) {
    int b = t * 7 + j;
    c[j] = (b < NB) ? min(bcur[b], BCAP) : 0;
    s += c[j];
  }
  sd[t] = s; __syncthreads();
  for (int off = 1; off < 256; off <<= 1) {
    int v = (t >= off) ? sd[t - off] : 0;
    __syncthreads(); sd[t] += v; __syncthreads();
  }
  int run = sd[t] - s;
  #pragma unroll
  for (int j = 0; j < 7; ++j) {
    int b = t * 7 + j;
    if (b < NB) { bbase[b] = run; run += c[j]; }
  }
  if (t == 255) { bbase[NB] = run; row_start[NN] = run; }
}

// ---------------- pass 3: per-bucket CSR build (block-local dense writes) ----------------
__global__ __launch_bounds__(256) void k_build(const int* __restrict__ bcur,
    const int* __restrict__ bbase, const int* __restrict__ ebuf,
    int* __restrict__ row_start, int* __restrict__ srcs)
{
  __shared__ int lcnt[64];
  __shared__ int lofs[64];
  int b = blockIdx.x, tid = threadIdx.x;
  int n = min(bcur[b], BCAP);
  int bb = bbase[b];
  const int* eb = ebuf + b * BCAP;
  if (tid < 64) lcnt[tid] = 0;
  __syncthreads();
  for (int e = tid; e < n; e += 256) atomicAdd(&lcnt[eb[e] & 63], 1);
  __syncthreads();
  if (tid < 64) {
    int c = lcnt[tid];
    int incl = c;
    #pragma unroll
    for (int off = 1; off < 64; off <<= 1) {
      int v = __shfl_up(incl, off);
      if (tid >= off) incl += v;
    }
    int excl = incl - c;
    lofs[tid] = excl;
    int node = b * 64 + tid;
    if (node < NN) row_start[node] = bb + excl;
  }
  __syncthreads();
  if (tid < 64) lcnt[tid] = lofs[tid];
  __syncthreads();
  for (int e = tid; e < n; e += 256) {
    int w = eb[e];
    int p = atomicAdd(&lcnt[w & 63], 1);
    srcs[bb + p] = w >> 6;
  }
}

// ---------------- layer 1: 17-wide aggregate + (17->64) matmuls, relu, fp16 out ----------------
__global__ __launch_bounds__(256) void k_sage1(const float* __restrict__ h0,
    const int* __restrict__ row_start, const int* __restrict__ srcs,
    const float* __restrict__ Wl, const float* __restrict__ bl,
    const float* __restrict__ Wr, _Float16* __restrict__ h1)
{
  int wid = (blockIdx.x * 256 + threadIdx.x) >> 6;
  int lane = threadIdx.x & 63;
  if (wid >= NN) return;
  int i = __builtin_amdgcn_readfirstlane(wid);
  int rs = row_start[i], re = row_start[i + 1];
  int m = re - rs;
  const int* __restrict__ sl = srcs + rs;

  float hval = (lane < 17) ? h0[(size_t)i * 17 + lane] : 0.f;

  int g = lane / 17;            // 0..3 (group 3 idle)
  int k = lane - g * 17;
  float s = 0.f;
  if (g < 3) {
    for (int e = g; e < m; e += 3)
      s += h0[(size_t)sl[e] * 17 + k];
  }
  float t1 = __shfl(s, lane + 17);
  float t2 = __shfl(s, lane + 34);
  if (lane < 17) s += t1 + t2;

  float mean = s / fmaxf((float)m, 1.f);

  float acc = bl[lane];
  #pragma unroll
  for (int kk = 0; kk < 17; ++kk) {
    acc = fmaf(lanebc(mean, kk), Wl[kk * 64 + lane], acc);
    acc = fmaf(lanebc(hval, kk), Wr[kk * 64 + lane], acc);
  }
  h1[(size_t)i * 64 + lane] = (_Float16)fmaxf(acc, 0.f);
}

// ---------------- layers 2/3: 64-wide aggregate + matmuls + residual, relu ----------------
template <bool FINAL>
__global__ __launch_bounds__(256) void k_sage23(const _Float16* __restrict__ hin,
    const int* __restrict__ row_start, const int* __restrict__ srcs,
    const float* __restrict__ Wl, const float* __restrict__ bl,
    const float* __restrict__ Wr, const float* __restrict__ Wfc,
    const float* __restrict__ bfc, void* __restrict__ outp)
{
  int wid = (blockIdx.x * 256 + threadIdx.x) >> 6;
  int lane = threadIdx.x & 63;
  if (wid >= NN) return;
  int i = __builtin_amdgcn_readfirstlane(wid);
  int rs = row_start[i], re = row_start[i + 1];
  int m = re - rs;
  const int* __restrict__ sl = srcs + rs;

  float hval = (float)hin[(size_t)i * 64 + lane];

  float s = 0.f;
  int e = 0;
  for (; e + 7 < m; e += 8) {
    int s0 = sl[e],     s1 = sl[e + 1], s2 = sl[e + 2], s3 = sl[e + 3];
    int s4 = sl[e + 4], s5 = sl[e + 5], s6 = sl[e + 6], s7 = sl[e + 7];
    float a0 = (float)hin[(size_t)s0 * 64 + lane];
    float a1 = (float)hin[(size_t)s1 * 64 + lane];
    float a2 = (float)hin[(size_t)s2 * 64 + lane];
    float a3 = (float)hin[(size_t)s3 * 64 + lane];
    float a4 = (float)hin[(size_t)s4 * 64 + lane];
    float a5 = (float)hin[(size_t)s5 * 64 + lane];
    float a6 = (float)hin[(size_t)s6 * 64 + lane];
    float a7 = (float)hin[(size_t)s7 * 64 + lane];
    s += ((a0 + a1) + (a2 + a3)) + ((a4 + a5) + (a6 + a7));
  }
  for (; e < m; ++e) s += (float)hin[(size_t)sl[e] * 64 + lane];

  float mean = s / fmaxf((float)m, 1.f);

  float acc = bl[lane] + hval;   // residual
  #pragma unroll
  for (int kk = 0; kk < 64; ++kk) {
    acc = fmaf(lanebc(mean, kk), Wl[kk * 64 + lane], acc);
    acc = fmaf(lanebc(hval, kk), Wr[kk * 64 + lane], acc);
  }
  float v = fmaxf(acc, 0.f);

  if (!FINAL) {
    ((_Float16*)outp)[(size_t)i * 64 + lane] = (_Float16)v;
  } else {
    float p = v * Wfc[lane];
    #pragma unroll
    for (int off = 32; off; off >>= 1) p += __shfl_xor(p, off);
    if (lane == 0) ((float*)outp)[i] = p + bfc[0];
  }
}

// ---------------- launch ----------------
extern "C" void kernel_launch(void* const* d_in, const int* in_sizes, int n_in,
                              void* d_out, int out_size, void* d_ws, size_t ws_size,
                              hipStream_t stream)
{
  const float* x   = (const float*)d_in[0];
  const int*   ei  = (const int*)d_in[1];
  const float* We  = (const float*)d_in[2];
  const float* be  = (const float*)d_in[3];
  const float* lg  = (const float*)d_in[4];
  const float* lb  = (const float*)d_in[5];
  const float* Wl1 = (const float*)d_in[6];
  const float* bl1 = (const float*)d_in[7];
  const float* Wr1 = (const float*)d_in[8];
  const float* Wl2 = (const float*)d_in[9];
  const float* bl2 = (const float*)d_in[10];
  const float* Wr2 = (const float*)d_in[11];
  const float* Wl3 = (const float*)d_in[12];
  const float* bl3 = (const float*)d_in[13];
  const float* Wr3 = (const float*)d_in[14];
  const float* Wfc = (const float*)d_in[15];
  const float* bfc = (const float*)d_in[16];
  (void)in_sizes; (void)n_in; (void)out_size; (void)ws_size;

  size_t off = 0;
  auto carve = [&](size_t bytes) -> void* {
    void* p = (char*)d_ws + off;
    off += (bytes + 255) & ~(size_t)255;
    return p;
  };
  float*    h0  = (float*)carve((size_t)NN * 17 * 4);
  // union region: ebuf (16.0 MB) aliases h1+h2 (25.6 MB); ebuf dead before h1 written
  char*     uni = (char*)carve((size_t)NN * 64 * 2 * 2);
  int*      ebuf = (int*)uni;
  _Float16* h1  = (_Float16*)uni;
  _Float16* h2  = (_Float16*)(uni + (size_t)NN * 64 * 2);
  int*      row_start = (int*)carve((size_t)(NN + 1) * 4);
  int*      srcs = (int*)carve((size_t)NE * 4);
  int*      bcur = (int*)carve((size_t)NB * 4);
  int*      bbase = (int*)carve((size_t)(NB + 1) * 4);

  const int nblk_node = (NN + 255) / 256;          // 391
  const int nblk_bin  = (NE / 4 + 255) / 256;      // 3125
  const int nblk_wave = (NN + 3) / 4;              // 25000 (4 waves/block)

  hipMemsetAsync(bcur, 0, (size_t)NB * 4, stream);
  k_h0<<<nblk_node, 256, 0, stream>>>(x, We, be, lg, lb, h0);
  k_bin<<<nblk_bin, 256, 0, stream>>>(ei, bcur, ebuf);
  k_bscan<<<1, 256, 0, stream>>>(bcur, bbase, row_start);
  k_build<<<NB, 256, 0, stream>>>(bcur, bbase, ebuf, row_start, srcs);

  k_sage1<<<nblk_wave, 256, 0, stream>>>(h0, row_start, srcs, Wl1, bl1, Wr1, h1);
  k_sage23<false><<<nblk_wave, 256, 0, stream>>>(h1, row_start, srcs, Wl2, bl2, Wr2, nullptr, nullptr, h2);
  k_sage23<true ><<<nblk_wave, 256, 0, stream>>>(h2, row_start, srcs, Wl3, bl3, Wr3, Wfc, bfc, d_out);
}

// Round 5
// 538.858 us; speedup vs baseline: 1.7727x; 1.7727x over previous
//
#include <hip/hip_runtime.h>

#define NN 100000
#define NE 3200000
#define NB1 196      // ceil(NN/512): coarse buckets of 512 nodes
#define EPB 4096     // edges per partition block
#define NPB 782      // ceil(NE/EPB)

__device__ __forceinline__ float lanebc(float v, int l) {
  return __int_as_float(__builtin_amdgcn_readlane(__float_as_int(v), l));
}

// ---------------- h0 = concat(node_type, LN(onehot@We+be), other) ----------------
__global__ __launch_bounds__(256) void k_h0(const float* __restrict__ x,
    const float* __restrict__ We, const float* __restrict__ be,
    const float* __restrict__ lg, const float* __restrict__ lb,
    float* __restrict__ h0)
{
  __shared__ float xs[256 * 35];
  int tid = threadIdx.x;
  int base_node = blockIdx.x * 256;
  int nvalid = NN - base_node; if (nvalid > 256) nvalid = 256;
  int total = nvalid * 35;
  const float* srcp = x + (size_t)base_node * 35;
  for (int j = tid; j < total; j += 256) xs[j] = srcp[j];
  __syncthreads();
  int i = base_node + tid;
  if (i >= NN) return;
  const float* xr = xs + tid * 35;
  float e[8];
  #pragma unroll
  for (int j = 0; j < 8; ++j) e[j] = be[j];
  #pragma unroll
  for (int k = 0; k < 26; ++k) {
    float o = xr[6 + k];
    #pragma unroll
    for (int j = 0; j < 8; ++j) e[j] = fmaf(o, We[k * 8 + j], e[j]);
  }
  float mu = 0.f;
  #pragma unroll
  for (int j = 0; j < 8; ++j) mu += e[j];
  mu *= 0.125f;
  float var = 0.f;
  #pragma unroll
  for (int j = 0; j < 8; ++j) { float d = e[j] - mu; var = fmaf(d, d, var); }
  var *= 0.125f;
  float rs = rsqrtf(var + 1e-5f);
  float* hr = h0 + (size_t)i * 17;
  #pragma unroll
  for (int j = 0; j < 6; ++j) hr[j] = xr[j];
  #pragma unroll
  for (int j = 0; j < 8; ++j) hr[6 + j] = (e[j] - mu) * rs * lg[j] + lb[j];
  #pragma unroll
  for (int j = 0; j < 3; ++j) hr[14 + j] = xr[32 + j];
}

// ---------------- pass 0: exact coarse histogram ----------------
__global__ __launch_bounds__(256) void k_hist(const int* __restrict__ ei, int* __restrict__ gcur)
{
  __shared__ int hist[NB1];
  int tid = threadIdx.x;
  if (tid < NB1) hist[tid] = 0;
  __syncthreads();
  int base = blockIdx.x * EPB;
  int n = NE - base; if (n > EPB) n = EPB;
  const int* dp = ei + NE + base;
  for (int k = tid; k < n; k += 256) atomicAdd(&hist[dp[k] >> 9], 1);
  __syncthreads();
  if (tid < NB1 && hist[tid]) atomicAdd(&gcur[tid], hist[tid]);
}

// ---------------- pass 0b: scan bucket counts -> bases, reset cursors ----------------
__global__ __launch_bounds__(256) void k_bscan(int* __restrict__ gcur,
    int* __restrict__ bbase, int* __restrict__ row_start)
{
  __shared__ int sd[256];
  int tid = threadIdx.x;
  int v = (tid < NB1) ? gcur[tid] : 0;
  sd[tid] = v; __syncthreads();
  for (int off = 1; off < 256; off <<= 1) {
    int t = (tid >= off) ? sd[tid - off] : 0;
    __syncthreads(); sd[tid] += t; __syncthreads();
  }
  int excl = sd[tid] - v;
  if (tid < NB1) { bbase[tid] = excl; gcur[tid] = excl; }
  if (tid == 0) { bbase[NB1] = NE; row_start[NN] = NE; }
}

// ---------------- pass 1: LDS-binned partition into coarse buckets ----------------
__global__ __launch_bounds__(256) void k_partA(const int* __restrict__ ei,
    int* __restrict__ gcur, int* __restrict__ ebuf)
{
  __shared__ int hist[NB1];
  __shared__ int lofs[NB1];
  __shared__ int gb[NB1];
  __shared__ int cur[NB1];
  __shared__ int sd[256];
  __shared__ int stage[EPB];
  __shared__ unsigned char sbkt[EPB];
  int tid = threadIdx.x;
  int base = blockIdx.x * EPB;
  int n = NE - base; if (n > EPB) n = EPB;
  if (tid < NB1) hist[tid] = 0;
  __syncthreads();
  int s[16], d[16];
  #pragma unroll
  for (int k = 0; k < 16; ++k) {
    int idx = tid + k * 256;
    if (idx < n) {
      s[k] = ei[base + idx];
      d[k] = ei[NE + base + idx];
      atomicAdd(&hist[d[k] >> 9], 1);
    } else { s[k] = -1; d[k] = 0; }
  }
  __syncthreads();
  int v = (tid < NB1) ? hist[tid] : 0;
  sd[tid] = v; __syncthreads();
  for (int off = 1; off < 256; off <<= 1) {
    int t = (tid >= off) ? sd[tid - off] : 0;
    __syncthreads(); sd[tid] += t; __syncthreads();
  }
  int excl = sd[tid] - v;
  if (tid < NB1) {
    lofs[tid] = excl; cur[tid] = excl;
    if (v) gb[tid] = atomicAdd(&gcur[tid], v);
  }
  __syncthreads();
  #pragma unroll
  for (int k = 0; k < 16; ++k) {
    if (s[k] >= 0) {
      int b = d[k] >> 9;
      int p = atomicAdd(&cur[b], 1);
      stage[p] = (s[k] << 9) | (d[k] & 511);
      sbkt[p] = (unsigned char)b;
    }
  }
  __syncthreads();
  for (int p = tid; p < n; p += 256) {
    int b = sbkt[p];
    ebuf[gb[b] + (p - lofs[b])] = stage[p];
  }
}

// ---------------- pass 2: per-bucket CSR build ----------------
__global__ __launch_bounds__(512) void k_partB(const int* __restrict__ bbase,
    const int* __restrict__ ebuf, int* __restrict__ row_start, int* __restrict__ srcs)
{
  __shared__ int lcnt[512];
  __shared__ int sd[512];
  int b = blockIdx.x, tid = threadIdx.x;
  int start = bbase[b], end = bbase[b + 1];
  int n = end - start;
  lcnt[tid] = 0;
  __syncthreads();
  for (int e = tid; e < n; e += 512) atomicAdd(&lcnt[ebuf[start + e] & 511], 1);
  __syncthreads();
  int v = lcnt[tid];
  sd[tid] = v; __syncthreads();
  for (int off = 1; off < 512; off <<= 1) {
    int t = (tid >= off) ? sd[tid - off] : 0;
    __syncthreads(); sd[tid] += t; __syncthreads();
  }
  int excl = sd[tid] - v;
  int node = b * 512 + tid;
  if (node < NN) row_start[node] = start + excl;
  __syncthreads();
  lcnt[tid] = excl;
  __syncthreads();
  for (int e = tid; e < n; e += 512) {
    int w = ebuf[start + e];
    int p = atomicAdd(&lcnt[w & 511], 1);
    srcs[start + p] = w >> 9;
  }
}

// ---------------- layer 1: 17-wide aggregate + (17->64) matmuls, relu, fp16 out ----------------
__global__ __launch_bounds__(256) void k_sage1(const float* __restrict__ h0,
    const int* __restrict__ row_start, const int* __restrict__ srcs,
    const float* __restrict__ Wl, const float* __restrict__ bl,
    const float* __restrict__ Wr, _Float16* __restrict__ h1)
{
  int wid = (blockIdx.x * 256 + threadIdx.x) >> 6;
  int lane = threadIdx.x & 63;
  if (wid >= NN) return;
  int i = __builtin_amdgcn_readfirstlane(wid);
  int rs = row_start[i], re = row_start[i + 1];
  int m = re - rs;
  const int* __restrict__ sl = srcs + rs;

  float hval = (lane < 17) ? h0[(size_t)i * 17 + lane] : 0.f;

  int g = lane / 17;            // 0..3 (group 3 idle)
  int k = lane - g * 17;
  float s = 0.f;
  if (g < 3) {
    for (int e = g; e < m; e += 3)
      s += h0[(size_t)sl[e] * 17 + k];
  }
  float t1 = __shfl(s, lane + 17);
  float t2 = __shfl(s, lane + 34);
  if (lane < 17) s += t1 + t2;

  float mean = s / fmaxf((float)m, 1.f);

  float acc = bl[lane];
  #pragma unroll
  for (int kk = 0; kk < 17; ++kk) {
    acc = fmaf(lanebc(mean, kk), Wl[kk * 64 + lane], acc);
    acc = fmaf(lanebc(hval, kk), Wr[kk * 64 + lane], acc);
  }
  h1[(size_t)i * 64 + lane] = (_Float16)fmaxf(acc, 0.f);
}

// ---------------- layers 2/3: 64-wide aggregate + matmuls + residual, relu ----------------
template <bool FINAL>
__global__ __launch_bounds__(256) void k_sage23(const _Float16* __restrict__ hin,
    const int* __restrict__ row_start, const int* __restrict__ srcs,
    const float* __restrict__ Wl, const float* __restrict__ bl,
    const float* __restrict__ Wr, const float* __restrict__ Wfc,
    const float* __restrict__ bfc, void* __restrict__ outp)
{
  int wid = (blockIdx.x * 256 + threadIdx.x) >> 6;
  int lane = threadIdx.x & 63;
  if (wid >= NN) return;
  int i = __builtin_amdgcn_readfirstlane(wid);
  int rs = row_start[i], re = row_start[i + 1];
  int m = re - rs;
  const int* __restrict__ sl = srcs + rs;

  float hval = (float)hin[(size_t)i * 64 + lane];

  float s = 0.f;
  int e = 0;
  for (; e + 7 < m; e += 8) {
    int s0 = sl[e],     s1 = sl[e + 1], s2 = sl[e + 2], s3 = sl[e + 3];
    int s4 = sl[e + 4], s5 = sl[e + 5], s6 = sl[e + 6], s7 = sl[e + 7];
    float a0 = (float)hin[(size_t)s0 * 64 + lane];
    float a1 = (float)hin[(size_t)s1 * 64 + lane];
    float a2 = (float)hin[(size_t)s2 * 64 + lane];
    float a3 = (float)hin[(size_t)s3 * 64 + lane];
    float a4 = (float)hin[(size_t)s4 * 64 + lane];
    float a5 = (float)hin[(size_t)s5 * 64 + lane];
    float a6 = (float)hin[(size_t)s6 * 64 + lane];
    float a7 = (float)hin[(size_t)s7 * 64 + lane];
    s += ((a0 + a1) + (a2 + a3)) + ((a4 + a5) + (a6 + a7));
  }
  for (; e < m; ++e) s += (float)hin[(size_t)sl[e] * 64 + lane];

  float mean = s / fmaxf((float)m, 1.f);

  float acc = bl[lane] + hval;   // residual
  #pragma unroll
  for (int kk = 0; kk < 64; ++kk) {
    acc = fmaf(lanebc(mean, kk), Wl[kk * 64 + lane], acc);
    acc = fmaf(lanebc(hval, kk), Wr[kk * 64 + lane], acc);
  }
  float v = fmaxf(acc, 0.f);

  if (!FINAL) {
    ((_Float16*)outp)[(size_t)i * 64 + lane] = (_Float16)v;
  } else {
    float p = v * Wfc[lane];
    #pragma unroll
    for (int off = 32; off; off >>= 1) p += __shfl_xor(p, off);
    if (lane == 0) ((float*)outp)[i] = p + bfc[0];
  }
}

// ---------------- launch ----------------
extern "C" void kernel_launch(void* const* d_in, const int* in_sizes, int n_in,
                              void* d_out, int out_size, void* d_ws, size_t ws_size,
                              hipStream_t stream)
{
  const float* x   = (const float*)d_in[0];
  const int*   ei  = (const int*)d_in[1];
  const float* We  = (const float*)d_in[2];
  const float* be  = (const float*)d_in[3];
  const float* lg  = (const float*)d_in[4];
  const float* lb  = (const float*)d_in[5];
  const float* Wl1 = (const float*)d_in[6];
  const float* bl1 = (const float*)d_in[7];
  const float* Wr1 = (const float*)d_in[8];
  const float* Wl2 = (const float*)d_in[9];
  const float* bl2 = (const float*)d_in[10];
  const float* Wr2 = (const float*)d_in[11];
  const float* Wl3 = (const float*)d_in[12];
  const float* bl3 = (const float*)d_in[13];
  const float* Wr3 = (const float*)d_in[14];
  const float* Wfc = (const float*)d_in[15];
  const float* bfc = (const float*)d_in[16];
  (void)in_sizes; (void)n_in; (void)out_size; (void)ws_size;

  size_t off = 0;
  auto carve = [&](size_t bytes) -> void* {
    void* p = (char*)d_ws + off;
    off += (bytes + 255) & ~(size_t)255;
    return p;
  };
  float*    h0  = (float*)carve((size_t)NN * 17 * 4);
  // union: ebuf (12.8 MB, dead after k_partB) aliases h1 (12.8 MB, written in k_sage1)
  char*     uni = (char*)carve((size_t)NE * 4);
  int*      ebuf = (int*)uni;
  _Float16* h1  = (_Float16*)uni;
  _Float16* h2  = (_Float16*)carve((size_t)NN * 64 * 2);
  int*      row_start = (int*)carve((size_t)(NN + 1) * 4);
  int*      srcs = (int*)carve((size_t)NE * 4);
  int*      gcur = (int*)carve((size_t)NB1 * 4);
  int*      bbase = (int*)carve((size_t)(NB1 + 1) * 4);

  const int nblk_node = (NN + 255) / 256;          // 391
  const int nblk_wave = (NN + 3) / 4;              // 25000 (4 waves/block)

  hipMemsetAsync(gcur, 0, (size_t)NB1 * 4, stream);
  k_h0<<<nblk_node, 256, 0, stream>>>(x, We, be, lg, lb, h0);
  k_hist<<<NPB, 256, 0, stream>>>(ei, gcur);
  k_bscan<<<1, 256, 0, stream>>>(gcur, bbase, row_start);
  k_partA<<<NPB, 256, 0, stream>>>(ei, gcur, ebuf);
  k_partB<<<NB1, 512, 0, stream>>>(bbase, ebuf, row_start, srcs);

  k_sage1<<<nblk_wave, 256, 0, stream>>>(h0, row_start, srcs, Wl1, bl1, Wr1, h1);
  k_sage23<false><<<nblk_wave, 256, 0, stream>>>(h1, row_start, srcs, Wl2, bl2, Wr2, nullptr, nullptr, h2);
  k_sage23<true ><<<nblk_wave, 256, 0, stream>>>(h2, row_start, srcs, Wl3, bl3, Wr3, Wfc, bfc, d_out);
}

// Round 6
// 426.465 us; speedup vs baseline: 2.2398x; 1.2635x over previous
//
#include <hip/hip_runtime.h>

#define NN 100000
#define NE 3200000
#define NB1 196      // ceil(NN/512): coarse buckets of 512 nodes
#define EPB 4096     // edges per partition block
#define NPB 782      // ceil(NE/EPB)

typedef _Float16 half2v __attribute__((ext_vector_type(2)));
typedef _Float16 half8  __attribute__((ext_vector_type(8)));
typedef float    f32x4  __attribute__((ext_vector_type(4)));

// ---------------- h0 = concat(node_type, LN(onehot@We+be), other), fp16, padded to 32 ----------------
__global__ __launch_bounds__(256) void k_h0(const float* __restrict__ x,
    const float* __restrict__ We, const float* __restrict__ be,
    const float* __restrict__ lg, const float* __restrict__ lb,
    _Float16* __restrict__ h0p)
{
  __shared__ float xs[256 * 35];
  int tid = threadIdx.x;
  int base_node = blockIdx.x * 256;
  int nvalid = NN - base_node; if (nvalid > 256) nvalid = 256;
  int total = nvalid * 35;
  const float* srcp = x + (size_t)base_node * 35;
  for (int j = tid; j < total; j += 256) xs[j] = srcp[j];
  __syncthreads();
  int i = base_node + tid;
  if (i >= NN) return;
  const float* xr = xs + tid * 35;
  float e[8];
  #pragma unroll
  for (int j = 0; j < 8; ++j) e[j] = be[j];
  #pragma unroll
  for (int k = 0; k < 26; ++k) {
    float o = xr[6 + k];
    #pragma unroll
    for (int j = 0; j < 8; ++j) e[j] = fmaf(o, We[k * 8 + j], e[j]);
  }
  float mu = 0.f;
  #pragma unroll
  for (int j = 0; j < 8; ++j) mu += e[j];
  mu *= 0.125f;
  float var = 0.f;
  #pragma unroll
  for (int j = 0; j < 8; ++j) { float d = e[j] - mu; var = fmaf(d, d, var); }
  var *= 0.125f;
  float rs = rsqrtf(var + 1e-5f);

  _Float16 row[32];
  #pragma unroll
  for (int j = 0; j < 6; ++j) row[j] = (_Float16)xr[j];
  #pragma unroll
  for (int j = 0; j < 8; ++j) row[6 + j] = (_Float16)((e[j] - mu) * rs * lg[j] + lb[j]);
  #pragma unroll
  for (int j = 0; j < 3; ++j) row[14 + j] = (_Float16)xr[32 + j];
  #pragma unroll
  for (int j = 17; j < 32; ++j) row[j] = (_Float16)0.f;
  half8* dst = (half8*)(h0p + (size_t)i * 32);
  #pragma unroll
  for (int q = 0; q < 4; ++q) dst[q] = *(half8*)(row + q * 8);
}

// ---------------- pass 0: exact coarse histogram ----------------
__global__ __launch_bounds__(256) void k_hist(const int* __restrict__ ei, int* __restrict__ gcur)
{
  __shared__ int hist[NB1];
  int tid = threadIdx.x;
  if (tid < NB1) hist[tid] = 0;
  __syncthreads();
  int base = blockIdx.x * EPB;
  int n = NE - base; if (n > EPB) n = EPB;
  const int* dp = ei + NE + base;
  for (int k = tid; k < n; k += 256) atomicAdd(&hist[dp[k] >> 9], 1);
  __syncthreads();
  if (tid < NB1 && hist[tid]) atomicAdd(&gcur[tid], hist[tid]);
}

// ---------------- pass 0b: scan bucket counts -> bases, reset cursors ----------------
__global__ __launch_bounds__(256) void k_bscan(int* __restrict__ gcur,
    int* __restrict__ bbase, int* __restrict__ row_start)
{
  __shared__ int sd[256];
  int tid = threadIdx.x;
  int v = (tid < NB1) ? gcur[tid] : 0;
  sd[tid] = v; __syncthreads();
  for (int off = 1; off < 256; off <<= 1) {
    int t = (tid >= off) ? sd[tid - off] : 0;
    __syncthreads(); sd[tid] += t; __syncthreads();
  }
  int excl = sd[tid] - v;
  if (tid < NB1) { bbase[tid] = excl; gcur[tid] = excl; }
  if (tid == 0) { bbase[NB1] = NE; row_start[NN] = NE; }
}

// ---------------- pass 1: LDS-binned partition into coarse buckets ----------------
__global__ __launch_bounds__(256) void k_partA(const int* __restrict__ ei,
    int* __restrict__ gcur, int* __restrict__ ebuf)
{
  __shared__ int hist[NB1];
  __shared__ int lofs[NB1];
  __shared__ int gb[NB1];
  __shared__ int cur[NB1];
  __shared__ int sd[256];
  __shared__ int stage[EPB];
  __shared__ unsigned char sbkt[EPB];
  int tid = threadIdx.x;
  int base = blockIdx.x * EPB;
  int n = NE - base; if (n > EPB) n = EPB;
  if (tid < NB1) hist[tid] = 0;
  __syncthreads();
  int s[16], d[16];
  #pragma unroll
  for (int k = 0; k < 16; ++k) {
    int idx = tid + k * 256;
    if (idx < n) {
      s[k] = ei[base + idx];
      d[k] = ei[NE + base + idx];
      atomicAdd(&hist[d[k] >> 9], 1);
    } else { s[k] = -1; d[k] = 0; }
  }
  __syncthreads();
  int v = (tid < NB1) ? hist[tid] : 0;
  sd[tid] = v; __syncthreads();
  for (int off = 1; off < 256; off <<= 1) {
    int t = (tid >= off) ? sd[tid - off] : 0;
    __syncthreads(); sd[tid] += t; __syncthreads();
  }
  int excl = sd[tid] - v;
  if (tid < NB1) {
    lofs[tid] = excl; cur[tid] = excl;
    if (v) gb[tid] = atomicAdd(&gcur[tid], v);
  }
  __syncthreads();
  #pragma unroll
  for (int k = 0; k < 16; ++k) {
    if (s[k] >= 0) {
      int b = d[k] >> 9;
      int p = atomicAdd(&cur[b], 1);
      stage[p] = (s[k] << 9) | (d[k] & 511);
      sbkt[p] = (unsigned char)b;
    }
  }
  __syncthreads();
  for (int p = tid; p < n; p += 256) {
    int b = sbkt[p];
    ebuf[gb[b] + (p - lofs[b])] = stage[p];
  }
}

// ---------------- pass 2: per-bucket CSR build ----------------
__global__ __launch_bounds__(512) void k_partB(const int* __restrict__ bbase,
    const int* __restrict__ ebuf, int* __restrict__ row_start, int* __restrict__ srcs)
{
  __shared__ int lcnt[512];
  __shared__ int sd[512];
  int b = blockIdx.x, tid = threadIdx.x;
  int start = bbase[b], end = bbase[b + 1];
  int n = end - start;
  lcnt[tid] = 0;
  __syncthreads();
  for (int e = tid; e < n; e += 512) atomicAdd(&lcnt[ebuf[start + e] & 511], 1);
  __syncthreads();
  int v = lcnt[tid];
  sd[tid] = v; __syncthreads();
  for (int off = 1; off < 512; off <<= 1) {
    int t = (tid >= off) ? sd[tid - off] : 0;
    __syncthreads(); sd[tid] += t; __syncthreads();
  }
  int excl = sd[tid] - v;
  int node = b * 512 + tid;
  if (node < NN) row_start[node] = start + excl;
  __syncthreads();
  lcnt[tid] = excl;
  __syncthreads();
  for (int e = tid; e < n; e += 512) {
    int w = ebuf[start + e];
    int p = atomicAdd(&lcnt[w & 511], 1);
    srcs[start + p] = w >> 9;
  }
}

// ---------------- aggregate: mean of neighbor rows (W = 32 or 64 fp16 features) ----------------
template <int W>
__global__ __launch_bounds__(256) void k_agg(const _Float16* __restrict__ hin,
    const int* __restrict__ row_start, const int* __restrict__ srcs,
    _Float16* __restrict__ meanout)
{
  int wid = (blockIdx.x * 256 + threadIdx.x) >> 6;
  int lane = threadIdx.x & 63;
  if (wid >= NN) return;
  int i = __builtin_amdgcn_readfirstlane(wid);
  int rs = row_start[i], re = row_start[i + 1];
  int m = re - rs;
  constexpr int GE = (W == 32) ? 4 : 2;           // edges in flight per iteration
  int g = (W == 32) ? (lane >> 4) : (lane >> 5);  // edge subgroup
  int f = (W == 32) ? (lane & 15) : (lane & 31);  // feature-pair index
  const int* __restrict__ sp = srcs + rs;

  float s0 = 0.f, s1 = 0.f;
  #pragma unroll 4
  for (int e = g; e < m; e += GE) {
    int src = sp[e];
    half2v v = *(const half2v*)(hin + (size_t)src * W + f * 2);
    s0 += (float)v[0];
    s1 += (float)v[1];
  }
  if (W == 32) { s0 += __shfl_xor(s0, 16); s1 += __shfl_xor(s1, 16); }
  s0 += __shfl_xor(s0, 32); s1 += __shfl_xor(s1, 32);
  float cm = fmaxf((float)m, 1.f);
  if (lane < W / 2) {
    half2v o; o[0] = (_Float16)(s0 / cm); o[1] = (_Float16)(s1 / cm);
    *(half2v*)(meanout + (size_t)i * W + lane * 2) = o;
  }
}

// ---------------- MFMA MLP: out = relu(mean@Wl + b + h@Wr [+ h]); FINAL fuses fc ----------------
// mfma_f32_16x16x32_f16 layouts (m89-verified family):
//   A: row=lane&15, k=(lane>>4)*8+j ; B: k=(lane>>4)*8+j, col=lane&15
//   D: col=lane&15, row=(lane>>4)*4+reg
template <int W, int KW, bool RES, bool FINAL>
__global__ __launch_bounds__(256) void k_mlp(const _Float16* __restrict__ mean,
    const _Float16* __restrict__ h,
    const float* __restrict__ Wl, const float* __restrict__ bl,
    const float* __restrict__ Wr,
    const float* __restrict__ Wfc, const float* __restrict__ bfc,
    void* __restrict__ outp)
{
  constexpr int NKB = W / 32;
  int wave = threadIdx.x >> 6;
  int base = (blockIdx.x * 4 + wave) * 16;
  if (base >= NN) return;
  int lane = threadIdx.x & 63;
  int c = lane & 15, kg = lane >> 4;

  half8 am[NKB], ah[NKB];
  #pragma unroll
  for (int kb = 0; kb < NKB; ++kb) {
    am[kb] = *(const half8*)(mean + (size_t)(base + c) * W + kb * 32 + kg * 8);
    ah[kb] = *(const half8*)(h    + (size_t)(base + c) * W + kb * 32 + kg * 8);
  }

  half8 bwl[4][NKB], bwr[4][NKB];
  #pragma unroll
  for (int nt = 0; nt < 4; ++nt)
    #pragma unroll
    for (int kb = 0; kb < NKB; ++kb)
      #pragma unroll
      for (int j = 0; j < 8; ++j) {
        int k = kb * 32 + kg * 8 + j;
        bwl[nt][kb][j] = (k < KW) ? (_Float16)Wl[k * 64 + nt * 16 + c] : (_Float16)0.f;
        bwr[nt][kb][j] = (k < KW) ? (_Float16)Wr[k * 64 + nt * 16 + c] : (_Float16)0.f;
      }

  f32x4 acc[4] = {f32x4{0,0,0,0}, f32x4{0,0,0,0}, f32x4{0,0,0,0}, f32x4{0,0,0,0}};
  #pragma unroll
  for (int nt = 0; nt < 4; ++nt)
    #pragma unroll
    for (int kb = 0; kb < NKB; ++kb) {
      acc[nt] = __builtin_amdgcn_mfma_f32_16x16x32_f16(am[kb], bwl[nt][kb], acc[nt], 0, 0, 0);
      acc[nt] = __builtin_amdgcn_mfma_f32_16x16x32_f16(ah[kb], bwr[nt][kb], acc[nt], 0, 0, 0);
    }

  if (!FINAL) {
    _Float16* hout = (_Float16*)outp;
    #pragma unroll
    for (int nt = 0; nt < 4; ++nt) {
      float bia = bl[nt * 16 + c];
      #pragma unroll
      for (int r = 0; r < 4; ++r) {
        int node = base + kg * 4 + r;
        float v = acc[nt][r] + bia;
        if (RES) v += (float)h[(size_t)node * 64 + nt * 16 + c];
        v = fmaxf(v, 0.f);
        hout[(size_t)node * 64 + nt * 16 + c] = (_Float16)v;
      }
    }
  } else {
    float wf = Wfc[0];  // placate compiler when unused
    (void)wf;
    #pragma unroll
    for (int r = 0; r < 4; ++r) {
      float p = 0.f;
      #pragma unroll
      for (int nt = 0; nt < 4; ++nt) {
        float v = acc[nt][r] + bl[nt * 16 + c];
        if (RES) v += (float)h[(size_t)(base + kg * 4 + r) * 64 + nt * 16 + c];
        v = fmaxf(v, 0.f);
        p = fmaf(v, Wfc[nt * 16 + c], p);
      }
      p += __shfl_xor(p, 1); p += __shfl_xor(p, 2);
      p += __shfl_xor(p, 4); p += __shfl_xor(p, 8);
      if (c == 0) ((float*)outp)[base + kg * 4 + r] = p + bfc[0];
    }
  }
}

// ---------------- launch ----------------
extern "C" void kernel_launch(void* const* d_in, const int* in_sizes, int n_in,
                              void* d_out, int out_size, void* d_ws, size_t ws_size,
                              hipStream_t stream)
{
  const float* x   = (const float*)d_in[0];
  const int*   ei  = (const int*)d_in[1];
  const float* We  = (const float*)d_in[2];
  const float* be  = (const float*)d_in[3];
  const float* lg  = (const float*)d_in[4];
  const float* lb  = (const float*)d_in[5];
  const float* Wl1 = (const float*)d_in[6];
  const float* bl1 = (const float*)d_in[7];
  const float* Wr1 = (const float*)d_in[8];
  const float* Wl2 = (const float*)d_in[9];
  const float* bl2 = (const float*)d_in[10];
  const float* Wr2 = (const float*)d_in[11];
  const float* Wl3 = (const float*)d_in[12];
  const float* bl3 = (const float*)d_in[13];
  const float* Wr3 = (const float*)d_in[14];
  const float* Wfc = (const float*)d_in[15];
  const float* bfc = (const float*)d_in[16];
  (void)in_sizes; (void)n_in; (void)out_size; (void)ws_size;

  size_t off = 0;
  auto carve = [&](size_t bytes) -> void* {
    void* p = (char*)d_ws + off;
    off += (bytes + 255) & ~(size_t)255;
    return p;
  };
  _Float16* h0p    = (_Float16*)carve((size_t)NN * 32 * 2);   // 6.4 MB
  _Float16* mean1  = (_Float16*)carve((size_t)NN * 32 * 2);   // 6.4 MB
  // union: ebuf (12.8 MB, dead after k_partB) aliases h1 (first written by k_mlp1, after partB)
  char*     uni    = (char*)carve((size_t)NE * 4);
  int*      ebuf   = (int*)uni;
  _Float16* h1     = (_Float16*)uni;
  _Float16* mean23 = (_Float16*)carve((size_t)NN * 64 * 2);   // 12.8 MB
  _Float16* h2     = (_Float16*)carve((size_t)NN * 64 * 2);   // 12.8 MB
  int*      row_start = (int*)carve((size_t)(NN + 1) * 4);
  int*      srcs   = (int*)carve((size_t)NE * 4);
  int*      gcur   = (int*)carve((size_t)NB1 * 4);
  int*      bbase  = (int*)carve((size_t)(NB1 + 1) * 4);

  const int nblk_node = (NN + 255) / 256;          // 391
  const int nblk_wave = (NN + 3) / 4;              // 25000 (4 waves/block, 1 wave/node)
  const int nblk_mlp  = (NN + 63) / 64;            // 1563 (4 waves/block, 16 nodes/wave)

  hipMemsetAsync(gcur, 0, (size_t)NB1 * 4, stream);
  k_h0<<<nblk_node, 256, 0, stream>>>(x, We, be, lg, lb, h0p);
  k_hist<<<NPB, 256, 0, stream>>>(ei, gcur);
  k_bscan<<<1, 256, 0, stream>>>(gcur, bbase, row_start);
  k_partA<<<NPB, 256, 0, stream>>>(ei, gcur, ebuf);
  k_partB<<<NB1, 512, 0, stream>>>(bbase, ebuf, row_start, srcs);

  // layer 1
  k_agg<32><<<nblk_wave, 256, 0, stream>>>(h0p, row_start, srcs, mean1);
  k_mlp<32, 17, false, false><<<nblk_mlp, 256, 0, stream>>>(mean1, h0p, Wl1, bl1, Wr1, nullptr, nullptr, h1);
  // layer 2
  k_agg<64><<<nblk_wave, 256, 0, stream>>>(h1, row_start, srcs, mean23);
  k_mlp<64, 64, true, false><<<nblk_mlp, 256, 0, stream>>>(mean23, h1, Wl2, bl2, Wr2, nullptr, nullptr, h2);
  // layer 3 + fc
  k_agg<64><<<nblk_wave, 256, 0, stream>>>(h2, row_start, srcs, mean23);
  k_mlp<64, 64, true, true><<<nblk_mlp, 256, 0, stream>>>(mean23, h2, Wl3, bl3, Wr3, Wfc, bfc, d_out);
}